// Round 8
// baseline (1737.144 us; speedup 1.0000x reference)
//
#include <hip/hip_runtime.h>

#define E_ 5
#define B_ 4096
#define F_ 9984
#define D_ 512
#define NSUB_ 13
#define SUBW_ 768   // F_/NSUB_

typedef _Float16 f16;
typedef __attribute__((ext_vector_type(4))) _Float16 f16x4;
typedef __attribute__((ext_vector_type(8))) _Float16 f16x8;
typedef __attribute__((ext_vector_type(16))) float f32x16;

// ===========================================================================
// GEMM core v5.1 (proven R5/R7): DMA staging (global_load_lds 16B),
// double-buffered LDS, counted vmcnt(8), raw barriers, 2x-unrolled K-loop
// w/ compile-time buffer select + precomputed per-lane LDS base offsets.
// Tile 128x128, 4 waves, 64x64 wave tile, mfma_f32_32x32x16_f16, FULL
// 4-plane split (frozen per R3: dropping W-lo flips argmax rows).
// R6 lesson: finer phases (BK16) regress. R7 lesson: setprio neutral here.
// Both GEMMs measured at ~760-900 TF = the 128^2 2-barrier structure
// ceiling; remaining lever is dispatch-tail quantization (this round).
// ===========================================================================
#define BK 32
#define PLANE_H 4096          // 128 rows * 32 halfs
#define BUF_H   16384         // 4 planes (Ahi,Alo,Bhi,Blo)

#define MFMA(a, b, c) __builtin_amdgcn_mfma_f32_32x32x16_f16((a), (b), (c), 0, 0, 0)

__device__ __forceinline__ void gload16(const f16* g, f16* l) {
    __builtin_amdgcn_global_load_lds(
        (const __attribute__((address_space(1))) void*)g,
        (__attribute__((address_space(3))) void*)l, 16, 0, 0);
}

// BOFF: compile-time buffer offset (0 or BUF_H), in halfs.
template<int BOFF>
__device__ __forceinline__ void computeK5(const f16* lds,
        int aA0s0, int aA0s1, int aA1s0, int aA1s1,
        int aB0s0, int aB0s1, int aB1s0, int aB1s1,
        f32x16 accm[2][2], f32x16 accx[2][2]) {
    #pragma unroll
    for (int sub = 0; sub < 2; ++sub) {
        const int oA0 = sub ? aA0s1 : aA0s0;
        const int oA1 = sub ? aA1s1 : aA1s0;
        const int oB0 = sub ? aB0s1 : aB0s0;
        const int oB1 = sub ? aB1s1 : aB1s0;
        f16x8 ah0 = *(const f16x8*)(lds + BOFF + 0*PLANE_H + oA0);
        f16x8 ah1 = *(const f16x8*)(lds + BOFF + 0*PLANE_H + oA1);
        f16x8 al0 = *(const f16x8*)(lds + BOFF + 1*PLANE_H + oA0);
        f16x8 al1 = *(const f16x8*)(lds + BOFF + 1*PLANE_H + oA1);
        f16x8 bh0 = *(const f16x8*)(lds + BOFF + 2*PLANE_H + oB0);
        f16x8 bh1 = *(const f16x8*)(lds + BOFF + 2*PLANE_H + oB1);
        f16x8 bl0 = *(const f16x8*)(lds + BOFF + 3*PLANE_H + oB0);
        f16x8 bl1 = *(const f16x8*)(lds + BOFF + 3*PLANE_H + oB1);
        accm[0][0] = MFMA(ah0, bh0, accm[0][0]);
        accm[0][1] = MFMA(ah0, bh1, accm[0][1]);
        accm[1][0] = MFMA(ah1, bh0, accm[1][0]);
        accm[1][1] = MFMA(ah1, bh1, accm[1][1]);
        accx[0][0] = MFMA(ah0, bl0, accx[0][0]);
        accx[0][0] = MFMA(al0, bh0, accx[0][0]);
        accx[0][1] = MFMA(ah0, bl1, accx[0][1]);
        accx[0][1] = MFMA(al0, bh1, accx[0][1]);
        accx[1][0] = MFMA(ah1, bl0, accx[1][0]);
        accx[1][0] = MFMA(al1, bh0, accx[1][0]);
        accx[1][1] = MFMA(ah1, bl1, accx[1][1]);
        accx[1][1] = MFMA(al1, bh1, accx[1][1]);
    }
}

// Wave w DMA-stages plane w (0=Ah,1=Al,2=Bh,3=Bl); source pre-XOR'd so the
// linear LDS image matches the swizzled reads (c ^ ((row>>1)&3), involution).
// nk MUST be even (dec 16, enc 78/156/312).
__device__ __forceinline__ void gemm_core5(
    const f16* __restrict__ Ah, const f16* __restrict__ Al, int sA,
    const f16* __restrict__ Bh, const f16* __restrict__ Bl, int sB,
    int nk, f16* lds, int t, int wm, int wn, int l31, int g,
    f32x16 accm[2][2], f32x16 accx[2][2])
{
    const int lane = t & 63, wid = t >> 6;
    const int lrow = lane >> 2, lch = lane & 3;
    const f16* gp = (wid == 0) ? Ah : (wid == 1) ? Al : (wid == 2) ? Bh : Bl;
    const int gs = (wid < 2) ? sA : sB;

    const f16* gps[8];
    int ldoff[8];
    #pragma unroll
    for (int s = 0; s < 8; ++s) {
        const int row = s * 16 + lrow;
        gps[s] = gp + (size_t)row * gs + ((lch ^ ((row >> 1) & 3)) << 3);
        ldoff[s] = wid * PLANE_H + s * (16 * BK);
    }

    // per-lane LDS read base offsets (halfs), loop-invariant
    const int rowA0 = wm + l31,      rowA1 = wm + 32 + l31;
    const int rowB0 = wn + l31,      rowB1 = wn + 32 + l31;
    const int kA0 = (rowA0 >> 1) & 3, kA1 = (rowA1 >> 1) & 3;
    const int kB0 = (rowB0 >> 1) & 3, kB1 = (rowB1 >> 1) & 3;
    const int aA0s0 = rowA0 * BK + (((0 + g) ^ kA0) << 3);
    const int aA0s1 = rowA0 * BK + (((2 + g) ^ kA0) << 3);
    const int aA1s0 = rowA1 * BK + (((0 + g) ^ kA1) << 3);
    const int aA1s1 = rowA1 * BK + (((2 + g) ^ kA1) << 3);
    const int aB0s0 = rowB0 * BK + (((0 + g) ^ kB0) << 3);
    const int aB0s1 = rowB0 * BK + (((2 + g) ^ kB0) << 3);
    const int aB1s0 = rowB1 * BK + (((0 + g) ^ kB1) << 3);
    const int aB1s1 = rowB1 * BK + (((2 + g) ^ kB1) << 3);

    // prologue: stage K-step 0 into buf0; advance pointers to K-step 1
    #pragma unroll
    for (int s = 0; s < 8; ++s)
        gload16(gps[s], lds + ldoff[s]);
    #pragma unroll
    for (int s = 0; s < 8; ++s)
        gps[s] += BK;

    for (int kt = 0; kt < nk; kt += 2) {
        // ---- body A: compute buf0 (kt), prefetch kt+1 -> buf1 (always valid)
        #pragma unroll
        for (int s = 0; s < 8; ++s)
            gload16(gps[s], lds + BUF_H + ldoff[s]);
        #pragma unroll
        for (int s = 0; s < 8; ++s)
            gps[s] += BK;
        asm volatile("s_waitcnt vmcnt(8)" ::: "memory");
        __builtin_amdgcn_s_barrier();
        __builtin_amdgcn_sched_barrier(0);
        computeK5<0>(lds, aA0s0, aA0s1, aA1s0, aA1s1,
                     aB0s0, aB0s1, aB1s0, aB1s1, accm, accx);
        __builtin_amdgcn_sched_barrier(0);
        __builtin_amdgcn_s_barrier();
        __builtin_amdgcn_sched_barrier(0);

        // ---- body B: compute buf1 (kt+1), prefetch kt+2 -> buf0 (if any)
        if (kt + 2 < nk) {
            #pragma unroll
            for (int s = 0; s < 8; ++s)
                gload16(gps[s], lds + ldoff[s]);
            #pragma unroll
            for (int s = 0; s < 8; ++s)
                gps[s] += BK;
            asm volatile("s_waitcnt vmcnt(8)" ::: "memory");
        } else {
            asm volatile("s_waitcnt vmcnt(0)" ::: "memory");
        }
        __builtin_amdgcn_s_barrier();
        __builtin_amdgcn_sched_barrier(0);
        computeK5<BUF_H>(lds, aA0s0, aA0s1, aA1s0, aA1s1,
                         aB0s0, aB0s1, aB1s0, aB1s1, accm, accx);
        __builtin_amdgcn_sched_barrier(0);
        __builtin_amdgcn_s_barrier();
        __builtin_amdgcn_sched_barrier(0);
    }
}

// ---------------------------------------------------------------------------
// Pre-split kernels
// ---------------------------------------------------------------------------
__global__ __launch_bounds__(256) void split_x(const float* __restrict__ x,
                                               f16* __restrict__ xhi, f16* __restrict__ xlo) {
    size_t i = ((size_t)blockIdx.x * 256 + threadIdx.x) * 4;
    float4 v = *(const float4*)&x[i];
    float vv[4] = {v.x, v.y, v.z, v.w};
    f16x4 h, l;
    #pragma unroll
    for (int k = 0; k < 4; ++k) {
        f16 hh = (f16)vv[k];
        h[k] = hh;
        l[k] = (f16)((vv[k] - (float)hh) * 2048.0f);
    }
    *(f16x4*)&xhi[i] = h;
    *(f16x4*)&xlo[i] = l;
}

// W[e][R][C] f32 -> transposed planes [e][C][R] fp16, scaled x64, lo x2048.
__global__ __launch_bounds__(256) void splitT_W(const float* __restrict__ W,
                                                f16* __restrict__ Thi, f16* __restrict__ Tlo,
                                                int R, int C) {
    __shared__ float tile[64][65];
    const int rt = blockIdx.x, ct = blockIdx.y, e = blockIdx.z;
    const int t = threadIdx.x;
    const int r0 = rt * 64, c0 = ct * 64;
    const int tr = t >> 4, tc4 = (t & 15) * 4;
    const float* Wp = W + (size_t)e * R * C;
    #pragma unroll
    for (int p = 0; p < 4; ++p) {
        float4 v = *(const float4*)&Wp[(size_t)(r0 + tr + p*16) * C + c0 + tc4];
        tile[tr + p*16][tc4 + 0] = v.x;
        tile[tr + p*16][tc4 + 1] = v.y;
        tile[tr + p*16][tc4 + 2] = v.z;
        tile[tr + p*16][tc4 + 3] = v.w;
    }
    __syncthreads();
    f16* Th = Thi + (size_t)e * R * C;
    f16* Tl = Tlo + (size_t)e * R * C;
    #pragma unroll
    for (int p = 0; p < 4; ++p) {
        const int cr = tr + p*16;
        f16x4 h, l;
        #pragma unroll
        for (int k = 0; k < 4; ++k) {
            float v = tile[tc4 + k][cr] * 64.0f;
            f16 hh = (f16)v;
            h[k] = hh;
            l[k] = (f16)((v - (float)hh) * 2048.0f);
        }
        size_t off = (size_t)(c0 + cr) * R + r0 + tc4;
        *(f16x4*)&Th[off] = h;
        *(f16x4*)&Tl[off] = l;
    }
}

// ---------------------------------------------------------------------------
// Encoder GEMM: supertile grid (proven R4), core5. blockIdx.z = split-K.
// ks=4 -> 2560 blocks = 5.0 exact occupancy rounds (vs ks=2: 2.5 rounds,
// half-round tail at ~50% occupancy).
// ---------------------------------------------------------------------------
__global__ __launch_bounds__(256, 2) void mm_enc2(
    const f16* __restrict__ xhi, const f16* __restrict__ xlo,
    const f16* __restrict__ wthi, const f16* __restrict__ wtlo,
    const float* __restrict__ bias, int Kloc,
    f16* __restrict__ outHi, f16* __restrict__ outLo)
{
    __shared__ __align__(16) f16 lds[2 * BUF_H];
    const int gx = blockIdx.x;         // 0..79
    const int de = gx % 20;            // dt = de&3, e = de>>2
    const int bl = gx / 20;            // 0..3
    const int bt = blockIdx.y * 4 + bl; // 0..31
    const int ks = blockIdx.z;
    const int dt = de & 3, e = de >> 2;
    const int koff = ks * Kloc;
    const int t = threadIdx.x, lane = t & 63, l31 = lane & 31, g = lane >> 5, wid = t >> 6;
    const int wm = (wid >> 1) * 64, wn = (wid & 1) * 64;
    const f16* Ah = xhi + (size_t)bt * 128 * F_ + koff;
    const f16* Al = xlo + (size_t)bt * 128 * F_ + koff;
    const f16* Bh = wthi + ((size_t)e * D_ + dt * 128) * F_ + koff;
    const f16* Bl = wtlo + ((size_t)e * D_ + dt * 128) * F_ + koff;
    f32x16 accm[2][2] = {}, accx[2][2] = {};
    gemm_core5(Ah, Al, F_, Bh, Bl, F_, Kloc / BK, lds, t, wm, wn, l31, g, accm, accx);

    f16* oH = outHi + (size_t)ks * E_ * B_ * D_;
    f16* oL = outLo + (size_t)ks * E_ * B_ * D_;
    #pragma unroll
    for (int fn = 0; fn < 2; ++fn) {
        const int d = dt * 128 + wn + fn * 32 + l31;
        const float be = bias ? bias[e * D_ + d] : 0.0f;
        #pragma unroll
        for (int fm = 0; fm < 2; ++fm) {
            #pragma unroll
            for (int r = 0; r < 16; ++r) {
                float v = (accm[fm][fn][r] + accx[fm][fn][r] * (1.0f/2048.0f)) * (1.0f/64.0f) + be;
                int brow = bt * 128 + wm + fm * 32 + (r & 3) + 8 * (r >> 2) + 4 * g;
                size_t off = ((size_t)e * B_ + brow) * D_ + d;
                f16 h = (f16)v;
                oH[off] = h;
                oL[off] = (f16)((v - (float)h) * 2048.0f);
            }
        }
    }
}

// combine nks split-K partials + bias -> final hi/lo planes
__global__ __launch_bounds__(256) void combine_k(
    const f16* __restrict__ pH, const f16* __restrict__ pL,
    const float* __restrict__ b_enc, int nks,
    f16* __restrict__ oH, f16* __restrict__ oL)
{
    const size_t NP = (size_t)E_ * B_ * D_;
    size_t i = ((size_t)blockIdx.x * 256 + threadIdx.x) * 8;
    const int d = (int)(i % D_);
    const int e = (int)(i / ((size_t)B_ * D_));
    float v[8];
    #pragma unroll
    for (int k = 0; k < 8; ++k) v[k] = b_enc[e * D_ + d + k];
    for (int ks = 0; ks < nks; ++ks) {
        f16x8 h = *(const f16x8*)(pH + (size_t)ks * NP + i);
        f16x8 l = *(const f16x8*)(pL + (size_t)ks * NP + i);
        #pragma unroll
        for (int k = 0; k < 8; ++k)
            v[k] += (float)h[k] + (float)l[k] * (1.0f/2048.0f);
    }
    f16x8 oh, ol;
    #pragma unroll
    for (int k = 0; k < 8; ++k) {
        f16 hh = (f16)v[k];
        oh[k] = hh;
        ol[k] = (f16)((v[k] - (float)hh) * 2048.0f);
    }
    *(f16x8*)&oH[i] = oh;
    *(f16x8*)&oL[i] = ol;
}

// ---------------------------------------------------------------------------
// Decoder GEMM: core5 + coalesced x-tile LDS epilogue (R5). Grid: bt
// fastest (proven R2: FETCH 2.6GB -> 1.06GB).
// ---------------------------------------------------------------------------
__global__ __launch_bounds__(256, 2) void mm_dec2(
    const f16* __restrict__ wthi, const f16* __restrict__ wtlo,
    const f16* __restrict__ ohi, const f16* __restrict__ olo,
    const float* __restrict__ b_dec, const float* __restrict__ x,
    float* __restrict__ ijbuf)
{
    // 66560 B: max(2*BUF_H*2 = 65536, xs = 2*128*65*4 = 66560)
    __shared__ __align__(16) f16 lds[33280];
    const int bt = blockIdx.x;              // 0..31  (fastest: shares W-tile)
    const int ft = blockIdx.y;              // 0..5
    const int se = blockIdx.z;              // s*5 + e (slowest)
    const int e = se % 5, s = se / 5;
    const int t = threadIdx.x, lane = t & 63, l31 = lane & 31, g = lane >> 5, wid = t >> 6;
    const int wm = (wid >> 1) * 64, wn = (wid & 1) * 64;
    const int f0blk = s * SUBW_ + ft * 128;
    const f16* Ah = wthi + ((size_t)e * F_ + f0blk) * D_;
    const f16* Al = wtlo + ((size_t)e * F_ + f0blk) * D_;
    const f16* Bh = ohi + ((size_t)e * B_ + bt * 128) * D_;
    const f16* Bl = olo + ((size_t)e * B_ + bt * 128) * D_;
    f32x16 accm[2][2] = {}, accx[2][2] = {};
    gemm_core5(Ah, Al, D_, Bh, Bl, D_, D_ / BK, lds, t, wm, wn, l31, g, accm, accx);

    // ---- stage x tile [128 b][128 f] coalesced into LDS (core ended w/ barrier)
    float* xs = (float*)lds;                // two halves of [128][65] floats
    {
        const int fb = (t & 31) * 4;        // 0..124, multiple of 4
        const int h  = fb >> 6, fl = fb & 63;
        float* dst0 = xs + h * (128 * 65) + fl;
        const float* src = &x[(size_t)(bt * 128 + (t >> 5)) * F_ + f0blk + fb];
        #pragma unroll
        for (int it = 0; it < 16; ++it) {
            const int b = (t >> 5) + it * 8;
            float4 v = *(const float4*)(src + (size_t)it * 8 * F_);
            float* dst = dst0 + b * 65;
            dst[0] = v.x; dst[1] = v.y; dst[2] = v.z; dst[3] = v.w;
        }
    }
    __syncthreads();

    const float* xsw = xs + (wm >> 6) * (128 * 65);  // wave's f-half
    float ia[2] = {0.f, 0.f}, ja[2] = {0.f, 0.f};
    #pragma unroll
    for (int fm = 0; fm < 2; ++fm) {
        #pragma unroll
        for (int q = 0; q < 8; ++q) {
            const int r = q * 2;
            const int fl = fm * 32 + (r & 3) + 8 * (r >> 2) + 4 * g;   // even, <64
            const int fg = f0blk + wm + fl;
            const float2 bd = *(const float2*)&b_dec[(size_t)e * F_ + fg];
            #pragma unroll
            for (int fn = 0; fn < 2; ++fn) {
                const int bl_ = wn + fn * 32 + l31;
                const float x0 = xsw[bl_ * 65 + fl];
                const float x1 = xsw[bl_ * 65 + fl + 1];
                float y0 = (accm[fm][fn][r]     + accx[fm][fn][r]     * (1.0f/2048.0f)) * (1.0f/64.0f) + bd.x;
                float y1 = (accm[fm][fn][r + 1] + accx[fm][fn][r + 1] * (1.0f/2048.0f)) * (1.0f/64.0f) + bd.y;
                ia[fn] += y0 * x0 + y1 * x1;
                ja[fn] += y0 * x1 - y1 * x0;
            }
        }
    }
    #pragma unroll
    for (int fn = 0; fn < 2; ++fn) {
        ia[fn] += __shfl_xor(ia[fn], 32, 64);
        ja[fn] += __shfl_xor(ja[fn], 32, 64);
    }
    __syncthreads();                        // xs reads done before red overwrite
    // cross-wave (wm) reduction through lds scratch
    float* red = (float*)lds;   // [wc(2)][64][2]
    const int wr = wid >> 1, wc = wid & 1;
    if (wr == 0 && lane < 32) {
        #pragma unroll
        for (int fn = 0; fn < 2; ++fn) {
            red[(wc * 64 + fn * 32 + l31) * 2 + 0] = ia[fn];
            red[(wc * 64 + fn * 32 + l31) * 2 + 1] = ja[fn];
        }
    }
    __syncthreads();
    if (wr == 1 && lane < 32) {
        #pragma unroll
        for (int fn = 0; fn < 2; ++fn) {
            float gi = ia[fn] + red[(wc * 64 + fn * 32 + l31) * 2 + 0];
            float gj = ja[fn] + red[(wc * 64 + fn * 32 + l31) * 2 + 1];
            int b = bt * 128 + wc * 64 + fn * 32 + l31;
            size_t base = (((size_t)(e * NSUB_ + s)) * 6 + ft) * 2;
            ijbuf[(base + 0) * B_ + b] = gi;
            ijbuf[(base + 1) * B_ + b] = gj;
        }
    }
}

__global__ __launch_bounds__(256) void argmax2(const float* __restrict__ ijbuf, int* __restrict__ idx) {
    int b = blockIdx.x * 256 + threadIdx.x;
    float best = -1.0f; int bi = 0;
    for (int e = 0; e < E_; ++e) {
        float sc = 0.f;
        for (int s = 0; s < NSUB_; ++s) {
            float ii = 0.f, jj = 0.f;
            #pragma unroll
            for (int ft = 0; ft < 6; ++ft) {
                size_t base = (((size_t)(e * NSUB_ + s)) * 6 + ft) * 2;
                ii += ijbuf[base * B_ + b];
                jj += ijbuf[(base + 1) * B_ + b];
            }
            sc += ii * ii + jj * jj;
        }
        if (sc > best) { best = sc; bi = e; }
    }
    idx[b] = bi;
}

__global__ __launch_bounds__(256) void gather2(const f16* __restrict__ outHi, const f16* __restrict__ outLo,
                                               const int* __restrict__ idx, float* __restrict__ sel) {
    int tg = blockIdx.x * 256 + threadIdx.x;
    int b = tg >> 7, dq = (tg & 127) * 4;
    int e = idx[b];
    size_t off = ((size_t)e * B_ + b) * D_ + dq;
    f16x4 h = *(const f16x4*)&outHi[off];
    f16x4 l = *(const f16x4*)&outLo[off];
    float4 o;
    o.x = (float)h[0] + (float)l[0] * (1.0f/2048.0f);
    o.y = (float)h[1] + (float)l[1] * (1.0f/2048.0f);
    o.z = (float)h[2] + (float)l[2] * (1.0f/2048.0f);
    o.w = (float)h[3] + (float)l[3] * (1.0f/2048.0f);
    *(float4*)&sel[(size_t)b * D_ + dq] = o;
}

// ===========================================================================
// Fallback f32 path (round-1, proven) — used if workspace too small
// ===========================================================================
__global__ __launch_bounds__(256) void enc_gemm(const float* __restrict__ x,
                                                const float* __restrict__ W_enc,
                                                const float* __restrict__ b_enc,
                                                float* __restrict__ out)
{
    __shared__ float As[16][68];
    __shared__ float Bs[16][68];
    const int btile = blockIdx.x;
    const int en    = blockIdx.y;
    const int e  = en >> 3;
    const int n0 = (en & 7) * 64;
    const int b0 = btile * 64;
    const int tid = threadIdx.x;
    const int tx = tid & 15, ty = tid >> 4;
    const float* Wp = W_enc + (size_t)e * F_ * D_;
    const int arow = tid >> 2;
    const int ac4  = (tid & 3) * 4;
    const int bk   = tid >> 4;
    const int bn   = (tid & 15) * 4;
    float acc[4][4] = {};
    for (int k0 = 0; k0 < F_; k0 += 16) {
        float4 av = *(const float4*)&x[(size_t)(b0 + arow) * F_ + k0 + ac4];
        As[ac4 + 0][arow] = av.x; As[ac4 + 1][arow] = av.y;
        As[ac4 + 2][arow] = av.z; As[ac4 + 3][arow] = av.w;
        float4 bv = *(const float4*)&Wp[(size_t)(k0 + bk) * D_ + n0 + bn];
        *(float4*)&Bs[bk][bn] = bv;
        __syncthreads();
        #pragma unroll
        for (int k = 0; k < 16; ++k) {
            float4 a = *(const float4*)&As[k][ty * 4];
            float4 b = *(const float4*)&Bs[k][tx * 4];
            float ar[4] = {a.x, a.y, a.z, a.w};
            float br[4] = {b.x, b.y, b.z, b.w};
            #pragma unroll
            for (int r = 0; r < 4; ++r)
                #pragma unroll
                for (int c = 0; c < 4; ++c)
                    acc[r][c] += ar[r] * br[c];
        }
        __syncthreads();
    }
    float4 be = *(const float4*)&b_enc[e * D_ + n0 + tx * 4];
    #pragma unroll
    for (int r = 0; r < 4; ++r) {
        int b = b0 + ty * 4 + r;
        float4 o;
        o.x = acc[r][0] + be.x; o.y = acc[r][1] + be.y;
        o.z = acc[r][2] + be.z; o.w = acc[r][3] + be.w;
        *(float4*)&out[((size_t)e * B_ + b) * D_ + n0 + tx * 4] = o;
    }
}

__global__ __launch_bounds__(256) void dec_score(const float* __restrict__ out,
                                                 const float* __restrict__ W_dec,
                                                 const float* __restrict__ b_dec,
                                                 const float* __restrict__ x,
                                                 float* __restrict__ cbuf)
{
    __shared__ float As[16][68];
    __shared__ float Bs[16][68];
    const int btile = blockIdx.x;
    const int es    = blockIdx.y;
    const int e = es / 13;
    const int s = es % 13;
    const int b0 = btile * 64;
    const int fbase = s * SUBW_;
    const int tid = threadIdx.x;
    const int tx = tid & 15, ty = tid >> 4;
    const float* Ap = out   + (size_t)e * B_ * D_;
    const float* Wp = W_dec + (size_t)e * D_ * F_;
    const int arow = tid >> 2;
    const int ac4  = (tid & 3) * 4;
    const int bk   = tid >> 4;
    const int bn   = (tid & 15) * 4;
    float ip[4] = {}, jp[4] = {};
    for (int u = 0; u < 12; ++u) {
        const int f0 = fbase + u * 64;
        float acc[4][4] = {};
        for (int k0 = 0; k0 < D_; k0 += 16) {
            float4 av = *(const float4*)&Ap[(size_t)(b0 + arow) * D_ + k0 + ac4];
            As[ac4 + 0][arow] = av.x; As[ac4 + 1][arow] = av.y;
            As[ac4 + 2][arow] = av.z; As[ac4 + 3][arow] = av.w;
            float4 bv = *(const float4*)&Wp[(size_t)(k0 + bk) * F_ + f0 + bn];
            *(float4*)&Bs[bk][bn] = bv;
            __syncthreads();
            #pragma unroll
            for (int k = 0; k < 16; ++k) {
                float4 a = *(const float4*)&As[k][ty * 4];
                float4 b = *(const float4*)&Bs[k][tx * 4];
                float ar[4] = {a.x, a.y, a.z, a.w};
                float br[4] = {b.x, b.y, b.z, b.w};
                #pragma unroll
                for (int r = 0; r < 4; ++r)
                    #pragma unroll
                    for (int c = 0; c < 4; ++c)
                        acc[r][c] += ar[r] * br[c];
            }
            __syncthreads();
        }
        float4 bd = *(const float4*)&b_dec[(size_t)e * F_ + f0 + tx * 4];
        #pragma unroll
        for (int r = 0; r < 4; ++r) {
            int b = b0 + ty * 4 + r;
            float4 xv = *(const float4*)&x[(size_t)b * F_ + f0 + tx * 4];
            float y0 = acc[r][0] + bd.x;
            float y1 = acc[r][1] + bd.y;
            float y2 = acc[r][2] + bd.z;
            float y3 = acc[r][3] + bd.w;
            ip[r] += y0 * xv.x + y1 * xv.y + y2 * xv.z + y3 * xv.w;
            jp[r] += y0 * xv.y - y1 * xv.x + y2 * xv.w - y3 * xv.z;
        }
    }
    #pragma unroll
    for (int r = 0; r < 4; ++r) {
        float iv = ip[r], jv = jp[r];
        #pragma unroll
        for (int m = 1; m < 16; m <<= 1) {
            iv += __shfl_xor(iv, m, 64);
            jv += __shfl_xor(jv, m, 64);
        }
        if (tx == 0) {
            int b = b0 + ty * 4 + r;
            cbuf[((size_t)e * B_ + b) * NSUB_ + s] = iv * iv + jv * jv;
        }
    }
}

__global__ __launch_bounds__(256) void argmax_k(const float* __restrict__ cbuf,
                                                int* __restrict__ idx)
{
    int b = blockIdx.x * blockDim.x + threadIdx.x;
    if (b >= B_) return;
    float best = -1e30f;
    int bi = 0;
    for (int e = 0; e < E_; ++e) {
        float ssum = 0.f;
        #pragma unroll
        for (int s = 0; s < NSUB_; ++s)
            ssum += cbuf[((size_t)e * B_ + b) * NSUB_ + s];
        if (ssum > best) { best = ssum; bi = e; }
    }
    idx[b] = bi;
}

__global__ __launch_bounds__(256) void gather_k(const float* __restrict__ out,
                                                const int* __restrict__ idx,
                                                float* __restrict__ sel)
{
    int t = blockIdx.x * blockDim.x + threadIdx.x;
    int b = t >> 7;
    int c = (t & 127) * 4;
    int e = idx[b];
    *(float4*)&sel[(size_t)b * D_ + c] =
        *(const float4*)&out[((size_t)e * B_ + b) * D_ + c];
}

// ===========================================================================
extern "C" void kernel_launch(void* const* d_in, const int* in_sizes, int n_in,
                              void* d_out, int out_size, void* d_ws, size_t ws_size,
                              hipStream_t stream)
{
    const float* x     = (const float*)d_in[0];
    const float* W_enc = (const float*)d_in[1];
    const float* b_enc = (const float*)d_in[2];
    const float* W_dec = (const float*)d_in[3];
    const float* b_dec = (const float*)d_in[4];
    float* sel = (float*)d_out;

    const size_t szXplane = (size_t)B_ * F_ * sizeof(f16);        // 81,788,928
    const size_t szWplane = (size_t)E_ * F_ * D_ * sizeof(f16);   // 51,118,080
    const size_t szOplane = (size_t)E_ * B_ * D_ * sizeof(f16);   // 20,971,520
    const size_t szIJ     = (size_t)E_ * NSUB_ * 6 * 2 * B_ * sizeof(float); // 12,779,520
    const size_t need       = 2*szXplane + 2*szWplane + 2*szOplane + szIJ + (size_t)B_*4;
    const size_t needSplit2 = need + 4*szOplane;   // pH,pL x 2 partials
    const size_t needSplit4 = need + 8*szOplane;   // pH,pL x 4 partials

    if (ws_size >= need) {
        char* p = (char*)d_ws;
        f16* xhi  = (f16*)p; p += szXplane;
        f16* xlo  = (f16*)p; p += szXplane;
        f16* wthi = (f16*)p; p += szWplane;
        f16* wtlo = (f16*)p; p += szWplane;
        f16* ohi  = (f16*)p; p += szOplane;
        f16* olo  = (f16*)p; p += szOplane;
        float* ij = (float*)p; p += szIJ;
        int* idx  = (int*)p; p += (size_t)B_*4;

        split_x<<<39936, 256, 0, stream>>>(x, xhi, xlo);
        splitT_W<<<dim3(F_/64, D_/64, E_), 256, 0, stream>>>(W_enc, wthi, wtlo, F_, D_);

        if (ws_size >= needSplit4) {
            // ks=4: 2560 blocks = 5.0 exact rounds at 2 blocks/CU
            f16* pH = (f16*)p; p += 4*szOplane;
            f16* pL = (f16*)p;
            mm_enc2<<<dim3(80, 8, 4), 256, 0, stream>>>(xhi, xlo, wthi, wtlo,
                                                        nullptr, F_/4, pH, pL);
            combine_k<<<(E_*B_*D_)/(8*256), 256, 0, stream>>>(pH, pL, b_enc, 4, ohi, olo);
        } else if (ws_size >= needSplit2) {
            f16* pH = (f16*)p; p += 2*szOplane;
            f16* pL = (f16*)p;
            mm_enc2<<<dim3(80, 8, 2), 256, 0, stream>>>(xhi, xlo, wthi, wtlo,
                                                        nullptr, F_/2, pH, pL);
            combine_k<<<(E_*B_*D_)/(8*256), 256, 0, stream>>>(pH, pL, b_enc, 2, ohi, olo);
        } else {
            mm_enc2<<<dim3(80, 8, 1), 256, 0, stream>>>(xhi, xlo, wthi, wtlo,
                                                        b_enc, F_, ohi, olo);
        }
        splitT_W<<<dim3(D_/64, F_/64, E_), 256, 0, stream>>>(W_dec, wthi, wtlo, D_, F_);
        mm_dec2<<<dim3(32, 6, 65), 256, 0, stream>>>(wthi, wtlo, ohi, olo, b_dec, x, ij);
        argmax2<<<16, 256, 0, stream>>>(ij, idx);
        gather2<<<2048, 256, 0, stream>>>(ohi, olo, idx, sel);
    } else {
        float* out  = (float*)d_ws;
        float* cbuf = out + (size_t)E_ * B_ * D_;
        int*   idx  = (int*)(cbuf + (size_t)E_ * B_ * NSUB_);
        enc_gemm <<<dim3(64, 40), 256, 0, stream>>>(x, W_enc, b_enc, out);
        dec_score<<<dim3(64, 65), 256, 0, stream>>>(out, W_dec, b_dec, x, cbuf);
        argmax_k <<<dim3(B_ / 256), 256, 0, stream>>>(cbuf, idx);
        gather_k <<<dim3(B_ * D_ / 4 / 256), 256, 0, stream>>>(out, idx, sel);
    }
}

// Round 9
// 1706.073 us; speedup vs baseline: 1.0182x; 1.0182x over previous
//
#include <hip/hip_runtime.h>

#define E_ 5
#define B_ 4096
#define F_ 9984
#define D_ 512
#define NSUB_ 13
#define SUBW_ 768   // F_/NSUB_

typedef _Float16 f16;
typedef __attribute__((ext_vector_type(4))) _Float16 f16x4;
typedef __attribute__((ext_vector_type(8))) _Float16 f16x8;
typedef __attribute__((ext_vector_type(16))) float f32x16;

// ===========================================================================
// GEMM core v5.1 (proven R5/R7 — best verified config, 1709-1717 us):
// DMA staging (global_load_lds 16B), double-buffered LDS, counted vmcnt(8),
// raw barriers, 2x-unrolled K-loop w/ compile-time buffer select +
// precomputed per-lane LDS base offsets. Tile 128x128, 4 waves, 64x64 wave
// tile, mfma_f32_32x32x16_f16, FULL 4-plane split (frozen per R3: dropping
// W-lo flips argmax rows).
// Session ledger: R6 finer phases = -20%; R7 setprio = neutral; R8 ks=4
// split-K = -1% (no dispatch tail exists — scheduler backfills).
// enc ~900 TF = 128^2 2-barrier structure ceiling; 256^2 escape infeasible
// at 128 acc regs/wave (4-plane split).
// ===========================================================================
#define BK 32
#define PLANE_H 4096          // 128 rows * 32 halfs
#define BUF_H   16384         // 4 planes (Ahi,Alo,Bhi,Blo)

#define MFMA(a, b, c) __builtin_amdgcn_mfma_f32_32x32x16_f16((a), (b), (c), 0, 0, 0)

__device__ __forceinline__ void gload16(const f16* g, f16* l) {
    __builtin_amdgcn_global_load_lds(
        (const __attribute__((address_space(1))) void*)g,
        (__attribute__((address_space(3))) void*)l, 16, 0, 0);
}

// BOFF: compile-time buffer offset (0 or BUF_H), in halfs.
template<int BOFF>
__device__ __forceinline__ void computeK5(const f16* lds,
        int aA0s0, int aA0s1, int aA1s0, int aA1s1,
        int aB0s0, int aB0s1, int aB1s0, int aB1s1,
        f32x16 accm[2][2], f32x16 accx[2][2]) {
    #pragma unroll
    for (int sub = 0; sub < 2; ++sub) {
        const int oA0 = sub ? aA0s1 : aA0s0;
        const int oA1 = sub ? aA1s1 : aA1s0;
        const int oB0 = sub ? aB0s1 : aB0s0;
        const int oB1 = sub ? aB1s1 : aB1s0;
        f16x8 ah0 = *(const f16x8*)(lds + BOFF + 0*PLANE_H + oA0);
        f16x8 ah1 = *(const f16x8*)(lds + BOFF + 0*PLANE_H + oA1);
        f16x8 al0 = *(const f16x8*)(lds + BOFF + 1*PLANE_H + oA0);
        f16x8 al1 = *(const f16x8*)(lds + BOFF + 1*PLANE_H + oA1);
        f16x8 bh0 = *(const f16x8*)(lds + BOFF + 2*PLANE_H + oB0);
        f16x8 bh1 = *(const f16x8*)(lds + BOFF + 2*PLANE_H + oB1);
        f16x8 bl0 = *(const f16x8*)(lds + BOFF + 3*PLANE_H + oB0);
        f16x8 bl1 = *(const f16x8*)(lds + BOFF + 3*PLANE_H + oB1);
        accm[0][0] = MFMA(ah0, bh0, accm[0][0]);
        accm[0][1] = MFMA(ah0, bh1, accm[0][1]);
        accm[1][0] = MFMA(ah1, bh0, accm[1][0]);
        accm[1][1] = MFMA(ah1, bh1, accm[1][1]);
        accx[0][0] = MFMA(ah0, bl0, accx[0][0]);
        accx[0][0] = MFMA(al0, bh0, accx[0][0]);
        accx[0][1] = MFMA(ah0, bl1, accx[0][1]);
        accx[0][1] = MFMA(al0, bh1, accx[0][1]);
        accx[1][0] = MFMA(ah1, bl0, accx[1][0]);
        accx[1][0] = MFMA(al1, bh0, accx[1][0]);
        accx[1][1] = MFMA(ah1, bl1, accx[1][1]);
        accx[1][1] = MFMA(al1, bh1, accx[1][1]);
    }
}

// Wave w DMA-stages plane w (0=Ah,1=Al,2=Bh,3=Bl); source pre-XOR'd so the
// linear LDS image matches the swizzled reads (c ^ ((row>>1)&3), involution).
// nk MUST be even (dec 16, enc 156/312).
__device__ __forceinline__ void gemm_core5(
    const f16* __restrict__ Ah, const f16* __restrict__ Al, int sA,
    const f16* __restrict__ Bh, const f16* __restrict__ Bl, int sB,
    int nk, f16* lds, int t, int wm, int wn, int l31, int g,
    f32x16 accm[2][2], f32x16 accx[2][2])
{
    const int lane = t & 63, wid = t >> 6;
    const int lrow = lane >> 2, lch = lane & 3;
    const f16* gp = (wid == 0) ? Ah : (wid == 1) ? Al : (wid == 2) ? Bh : Bl;
    const int gs = (wid < 2) ? sA : sB;

    const f16* gps[8];
    int ldoff[8];
    #pragma unroll
    for (int s = 0; s < 8; ++s) {
        const int row = s * 16 + lrow;
        gps[s] = gp + (size_t)row * gs + ((lch ^ ((row >> 1) & 3)) << 3);
        ldoff[s] = wid * PLANE_H + s * (16 * BK);
    }

    // per-lane LDS read base offsets (halfs), loop-invariant
    const int rowA0 = wm + l31,      rowA1 = wm + 32 + l31;
    const int rowB0 = wn + l31,      rowB1 = wn + 32 + l31;
    const int kA0 = (rowA0 >> 1) & 3, kA1 = (rowA1 >> 1) & 3;
    const int kB0 = (rowB0 >> 1) & 3, kB1 = (rowB1 >> 1) & 3;
    const int aA0s0 = rowA0 * BK + (((0 + g) ^ kA0) << 3);
    const int aA0s1 = rowA0 * BK + (((2 + g) ^ kA0) << 3);
    const int aA1s0 = rowA1 * BK + (((0 + g) ^ kA1) << 3);
    const int aA1s1 = rowA1 * BK + (((2 + g) ^ kA1) << 3);
    const int aB0s0 = rowB0 * BK + (((0 + g) ^ kB0) << 3);
    const int aB0s1 = rowB0 * BK + (((2 + g) ^ kB0) << 3);
    const int aB1s0 = rowB1 * BK + (((0 + g) ^ kB1) << 3);
    const int aB1s1 = rowB1 * BK + (((2 + g) ^ kB1) << 3);

    // prologue: stage K-step 0 into buf0; advance pointers to K-step 1
    #pragma unroll
    for (int s = 0; s < 8; ++s)
        gload16(gps[s], lds + ldoff[s]);
    #pragma unroll
    for (int s = 0; s < 8; ++s)
        gps[s] += BK;

    for (int kt = 0; kt < nk; kt += 2) {
        // ---- body A: compute buf0 (kt), prefetch kt+1 -> buf1 (always valid)
        #pragma unroll
        for (int s = 0; s < 8; ++s)
            gload16(gps[s], lds + BUF_H + ldoff[s]);
        #pragma unroll
        for (int s = 0; s < 8; ++s)
            gps[s] += BK;
        asm volatile("s_waitcnt vmcnt(8)" ::: "memory");
        __builtin_amdgcn_s_barrier();
        __builtin_amdgcn_sched_barrier(0);
        computeK5<0>(lds, aA0s0, aA0s1, aA1s0, aA1s1,
                     aB0s0, aB0s1, aB1s0, aB1s1, accm, accx);
        __builtin_amdgcn_sched_barrier(0);
        __builtin_amdgcn_s_barrier();
        __builtin_amdgcn_sched_barrier(0);

        // ---- body B: compute buf1 (kt+1), prefetch kt+2 -> buf0 (if any)
        if (kt + 2 < nk) {
            #pragma unroll
            for (int s = 0; s < 8; ++s)
                gload16(gps[s], lds + ldoff[s]);
            #pragma unroll
            for (int s = 0; s < 8; ++s)
                gps[s] += BK;
            asm volatile("s_waitcnt vmcnt(8)" ::: "memory");
        } else {
            asm volatile("s_waitcnt vmcnt(0)" ::: "memory");
        }
        __builtin_amdgcn_s_barrier();
        __builtin_amdgcn_sched_barrier(0);
        computeK5<BUF_H>(lds, aA0s0, aA0s1, aA1s0, aA1s1,
                         aB0s0, aB0s1, aB1s0, aB1s1, accm, accx);
        __builtin_amdgcn_sched_barrier(0);
        __builtin_amdgcn_s_barrier();
        __builtin_amdgcn_sched_barrier(0);
    }
}

// ---------------------------------------------------------------------------
// Pre-split kernels
// ---------------------------------------------------------------------------
__global__ __launch_bounds__(256) void split_x(const float* __restrict__ x,
                                               f16* __restrict__ xhi, f16* __restrict__ xlo) {
    size_t i = ((size_t)blockIdx.x * 256 + threadIdx.x) * 4;
    float4 v = *(const float4*)&x[i];
    float vv[4] = {v.x, v.y, v.z, v.w};
    f16x4 h, l;
    #pragma unroll
    for (int k = 0; k < 4; ++k) {
        f16 hh = (f16)vv[k];
        h[k] = hh;
        l[k] = (f16)((vv[k] - (float)hh) * 2048.0f);
    }
    *(f16x4*)&xhi[i] = h;
    *(f16x4*)&xlo[i] = l;
}

// W[e][R][C] f32 -> transposed planes [e][C][R] fp16, scaled x64, lo x2048.
__global__ __launch_bounds__(256) void splitT_W(const float* __restrict__ W,
                                                f16* __restrict__ Thi, f16* __restrict__ Tlo,
                                                int R, int C) {
    __shared__ float tile[64][65];
    const int rt = blockIdx.x, ct = blockIdx.y, e = blockIdx.z;
    const int t = threadIdx.x;
    const int r0 = rt * 64, c0 = ct * 64;
    const int tr = t >> 4, tc4 = (t & 15) * 4;
    const float* Wp = W + (size_t)e * R * C;
    #pragma unroll
    for (int p = 0; p < 4; ++p) {
        float4 v = *(const float4*)&Wp[(size_t)(r0 + tr + p*16) * C + c0 + tc4];
        tile[tr + p*16][tc4 + 0] = v.x;
        tile[tr + p*16][tc4 + 1] = v.y;
        tile[tr + p*16][tc4 + 2] = v.z;
        tile[tr + p*16][tc4 + 3] = v.w;
    }
    __syncthreads();
    f16* Th = Thi + (size_t)e * R * C;
    f16* Tl = Tlo + (size_t)e * R * C;
    #pragma unroll
    for (int p = 0; p < 4; ++p) {
        const int cr = tr + p*16;
        f16x4 h, l;
        #pragma unroll
        for (int k = 0; k < 4; ++k) {
            float v = tile[tc4 + k][cr] * 64.0f;
            f16 hh = (f16)v;
            h[k] = hh;
            l[k] = (f16)((v - (float)hh) * 2048.0f);
        }
        size_t off = (size_t)(c0 + cr) * R + r0 + tc4;
        *(f16x4*)&Th[off] = h;
        *(f16x4*)&Tl[off] = l;
    }
}

// ---------------------------------------------------------------------------
// Encoder GEMM: supertile grid (proven R4), core5. blockIdx.z = split-K.
// ks=2 (R8 measured ks=4 as net-negative: no dispatch tail exists).
// ---------------------------------------------------------------------------
__global__ __launch_bounds__(256, 2) void mm_enc2(
    const f16* __restrict__ xhi, const f16* __restrict__ xlo,
    const f16* __restrict__ wthi, const f16* __restrict__ wtlo,
    const float* __restrict__ bias, int Kloc,
    f16* __restrict__ outHi, f16* __restrict__ outLo)
{
    __shared__ __align__(16) f16 lds[2 * BUF_H];
    const int gx = blockIdx.x;         // 0..79
    const int de = gx % 20;            // dt = de&3, e = de>>2
    const int bl = gx / 20;            // 0..3
    const int bt = blockIdx.y * 4 + bl; // 0..31
    const int ks = blockIdx.z;
    const int dt = de & 3, e = de >> 2;
    const int koff = ks * Kloc;
    const int t = threadIdx.x, lane = t & 63, l31 = lane & 31, g = lane >> 5, wid = t >> 6;
    const int wm = (wid >> 1) * 64, wn = (wid & 1) * 64;
    const f16* Ah = xhi + (size_t)bt * 128 * F_ + koff;
    const f16* Al = xlo + (size_t)bt * 128 * F_ + koff;
    const f16* Bh = wthi + ((size_t)e * D_ + dt * 128) * F_ + koff;
    const f16* Bl = wtlo + ((size_t)e * D_ + dt * 128) * F_ + koff;
    f32x16 accm[2][2] = {}, accx[2][2] = {};
    gemm_core5(Ah, Al, F_, Bh, Bl, F_, Kloc / BK, lds, t, wm, wn, l31, g, accm, accx);

    f16* oH = outHi + (size_t)ks * E_ * B_ * D_;
    f16* oL = outLo + (size_t)ks * E_ * B_ * D_;
    #pragma unroll
    for (int fn = 0; fn < 2; ++fn) {
        const int d = dt * 128 + wn + fn * 32 + l31;
        const float be = bias ? bias[e * D_ + d] : 0.0f;
        #pragma unroll
        for (int fm = 0; fm < 2; ++fm) {
            #pragma unroll
            for (int r = 0; r < 16; ++r) {
                float v = (accm[fm][fn][r] + accx[fm][fn][r] * (1.0f/2048.0f)) * (1.0f/64.0f) + be;
                int brow = bt * 128 + wm + fm * 32 + (r & 3) + 8 * (r >> 2) + 4 * g;
                size_t off = ((size_t)e * B_ + brow) * D_ + d;
                f16 h = (f16)v;
                oH[off] = h;
                oL[off] = (f16)((v - (float)h) * 2048.0f);
            }
        }
    }
}

// combine nks split-K partials + bias -> final hi/lo planes
__global__ __launch_bounds__(256) void combine_k(
    const f16* __restrict__ pH, const f16* __restrict__ pL,
    const float* __restrict__ b_enc, int nks,
    f16* __restrict__ oH, f16* __restrict__ oL)
{
    const size_t NP = (size_t)E_ * B_ * D_;
    size_t i = ((size_t)blockIdx.x * 256 + threadIdx.x) * 8;
    const int d = (int)(i % D_);
    const int e = (int)(i / ((size_t)B_ * D_));
    float v[8];
    #pragma unroll
    for (int k = 0; k < 8; ++k) v[k] = b_enc[e * D_ + d + k];
    for (int ks = 0; ks < nks; ++ks) {
        f16x8 h = *(const f16x8*)(pH + (size_t)ks * NP + i);
        f16x8 l = *(const f16x8*)(pL + (size_t)ks * NP + i);
        #pragma unroll
        for (int k = 0; k < 8; ++k)
            v[k] += (float)h[k] + (float)l[k] * (1.0f/2048.0f);
    }
    f16x8 oh, ol;
    #pragma unroll
    for (int k = 0; k < 8; ++k) {
        f16 hh = (f16)v[k];
        oh[k] = hh;
        ol[k] = (f16)((v[k] - (float)hh) * 2048.0f);
    }
    *(f16x8*)&oH[i] = oh;
    *(f16x8*)&oL[i] = ol;
}

// ---------------------------------------------------------------------------
// Decoder GEMM: core5 + coalesced x-tile LDS epilogue (R5). Grid: bt
// fastest (proven R2: FETCH 2.6GB -> 1.06GB).
// ---------------------------------------------------------------------------
__global__ __launch_bounds__(256, 2) void mm_dec2(
    const f16* __restrict__ wthi, const f16* __restrict__ wtlo,
    const f16* __restrict__ ohi, const f16* __restrict__ olo,
    const float* __restrict__ b_dec, const float* __restrict__ x,
    float* __restrict__ ijbuf)
{
    // 66560 B: max(2*BUF_H*2 = 65536, xs = 2*128*65*4 = 66560)
    __shared__ __align__(16) f16 lds[33280];
    const int bt = blockIdx.x;              // 0..31  (fastest: shares W-tile)
    const int ft = blockIdx.y;              // 0..5
    const int se = blockIdx.z;              // s*5 + e (slowest)
    const int e = se % 5, s = se / 5;
    const int t = threadIdx.x, lane = t & 63, l31 = lane & 31, g = lane >> 5, wid = t >> 6;
    const int wm = (wid >> 1) * 64, wn = (wid & 1) * 64;
    const int f0blk = s * SUBW_ + ft * 128;
    const f16* Ah = wthi + ((size_t)e * F_ + f0blk) * D_;
    const f16* Al = wtlo + ((size_t)e * F_ + f0blk) * D_;
    const f16* Bh = ohi + ((size_t)e * B_ + bt * 128) * D_;
    const f16* Bl = olo + ((size_t)e * B_ + bt * 128) * D_;
    f32x16 accm[2][2] = {}, accx[2][2] = {};
    gemm_core5(Ah, Al, D_, Bh, Bl, D_, D_ / BK, lds, t, wm, wn, l31, g, accm, accx);

    // ---- stage x tile [128 b][128 f] coalesced into LDS (core ended w/ barrier)
    float* xs = (float*)lds;                // two halves of [128][65] floats
    {
        const int fb = (t & 31) * 4;        // 0..124, multiple of 4
        const int h  = fb >> 6, fl = fb & 63;
        float* dst0 = xs + h * (128 * 65) + fl;
        const float* src = &x[(size_t)(bt * 128 + (t >> 5)) * F_ + f0blk + fb];
        #pragma unroll
        for (int it = 0; it < 16; ++it) {
            const int b = (t >> 5) + it * 8;
            float4 v = *(const float4*)(src + (size_t)it * 8 * F_);
            float* dst = dst0 + b * 65;
            dst[0] = v.x; dst[1] = v.y; dst[2] = v.z; dst[3] = v.w;
        }
    }
    __syncthreads();

    const float* xsw = xs + (wm >> 6) * (128 * 65);  // wave's f-half
    float ia[2] = {0.f, 0.f}, ja[2] = {0.f, 0.f};
    #pragma unroll
    for (int fm = 0; fm < 2; ++fm) {
        #pragma unroll
        for (int q = 0; q < 8; ++q) {
            const int r = q * 2;
            const int fl = fm * 32 + (r & 3) + 8 * (r >> 2) + 4 * g;   // even, <64
            const int fg = f0blk + wm + fl;
            const float2 bd = *(const float2*)&b_dec[(size_t)e * F_ + fg];
            #pragma unroll
            for (int fn = 0; fn < 2; ++fn) {
                const int bl_ = wn + fn * 32 + l31;
                const float x0 = xsw[bl_ * 65 + fl];
                const float x1 = xsw[bl_ * 65 + fl + 1];
                float y0 = (accm[fm][fn][r]     + accx[fm][fn][r]     * (1.0f/2048.0f)) * (1.0f/64.0f) + bd.x;
                float y1 = (accm[fm][fn][r + 1] + accx[fm][fn][r + 1] * (1.0f/2048.0f)) * (1.0f/64.0f) + bd.y;
                ia[fn] += y0 * x0 + y1 * x1;
                ja[fn] += y0 * x1 - y1 * x0;
            }
        }
    }
    #pragma unroll
    for (int fn = 0; fn < 2; ++fn) {
        ia[fn] += __shfl_xor(ia[fn], 32, 64);
        ja[fn] += __shfl_xor(ja[fn], 32, 64);
    }
    __syncthreads();                        // xs reads done before red overwrite
    // cross-wave (wm) reduction through lds scratch
    float* red = (float*)lds;   // [wc(2)][64][2]
    const int wr = wid >> 1, wc = wid & 1;
    if (wr == 0 && lane < 32) {
        #pragma unroll
        for (int fn = 0; fn < 2; ++fn) {
            red[(wc * 64 + fn * 32 + l31) * 2 + 0] = ia[fn];
            red[(wc * 64 + fn * 32 + l31) * 2 + 1] = ja[fn];
        }
    }
    __syncthreads();
    if (wr == 1 && lane < 32) {
        #pragma unroll
        for (int fn = 0; fn < 2; ++fn) {
            float gi = ia[fn] + red[(wc * 64 + fn * 32 + l31) * 2 + 0];
            float gj = ja[fn] + red[(wc * 64 + fn * 32 + l31) * 2 + 1];
            int b = bt * 128 + wc * 64 + fn * 32 + l31;
            size_t base = (((size_t)(e * NSUB_ + s)) * 6 + ft) * 2;
            ijbuf[(base + 0) * B_ + b] = gi;
            ijbuf[(base + 1) * B_ + b] = gj;
        }
    }
}

__global__ __launch_bounds__(256) void argmax2(const float* __restrict__ ijbuf, int* __restrict__ idx) {
    int b = blockIdx.x * 256 + threadIdx.x;
    float best = -1.0f; int bi = 0;
    for (int e = 0; e < E_; ++e) {
        float sc = 0.f;
        for (int s = 0; s < NSUB_; ++s) {
            float ii = 0.f, jj = 0.f;
            #pragma unroll
            for (int ft = 0; ft < 6; ++ft) {
                size_t base = (((size_t)(e * NSUB_ + s)) * 6 + ft) * 2;
                ii += ijbuf[base * B_ + b];
                jj += ijbuf[(base + 1) * B_ + b];
            }
            sc += ii * ii + jj * jj;
        }
        if (sc > best) { best = sc; bi = e; }
    }
    idx[b] = bi;
}

__global__ __launch_bounds__(256) void gather2(const f16* __restrict__ outHi, const f16* __restrict__ outLo,
                                               const int* __restrict__ idx, float* __restrict__ sel) {
    int tg = blockIdx.x * 256 + threadIdx.x;
    int b = tg >> 7, dq = (tg & 127) * 4;
    int e = idx[b];
    size_t off = ((size_t)e * B_ + b) * D_ + dq;
    f16x4 h = *(const f16x4*)&outHi[off];
    f16x4 l = *(const f16x4*)&outLo[off];
    float4 o;
    o.x = (float)h[0] + (float)l[0] * (1.0f/2048.0f);
    o.y = (float)h[1] + (float)l[1] * (1.0f/2048.0f);
    o.z = (float)h[2] + (float)l[2] * (1.0f/2048.0f);
    o.w = (float)h[3] + (float)l[3] * (1.0f/2048.0f);
    *(float4*)&sel[(size_t)b * D_ + dq] = o;
}

// ===========================================================================
// Fallback f32 path (round-1, proven) — used if workspace too small
// ===========================================================================
__global__ __launch_bounds__(256) void enc_gemm(const float* __restrict__ x,
                                                const float* __restrict__ W_enc,
                                                const float* __restrict__ b_enc,
                                                float* __restrict__ out)
{
    __shared__ float As[16][68];
    __shared__ float Bs[16][68];
    const int btile = blockIdx.x;
    const int en    = blockIdx.y;
    const int e  = en >> 3;
    const int n0 = (en & 7) * 64;
    const int b0 = btile * 64;
    const int tid = threadIdx.x;
    const int tx = tid & 15, ty = tid >> 4;
    const float* Wp = W_enc + (size_t)e * F_ * D_;
    const int arow = tid >> 2;
    const int ac4  = (tid & 3) * 4;
    const int bk   = tid >> 4;
    const int bn   = (tid & 15) * 4;
    float acc[4][4] = {};
    for (int k0 = 0; k0 < F_; k0 += 16) {
        float4 av = *(const float4*)&x[(size_t)(b0 + arow) * F_ + k0 + ac4];
        As[ac4 + 0][arow] = av.x; As[ac4 + 1][arow] = av.y;
        As[ac4 + 2][arow] = av.z; As[ac4 + 3][arow] = av.w;
        float4 bv = *(const float4*)&Wp[(size_t)(k0 + bk) * D_ + n0 + bn];
        *(float4*)&Bs[bk][bn] = bv;
        __syncthreads();
        #pragma unroll
        for (int k = 0; k < 16; ++k) {
            float4 a = *(const float4*)&As[k][ty * 4];
            float4 b = *(const float4*)&Bs[k][tx * 4];
            float ar[4] = {a.x, a.y, a.z, a.w};
            float br[4] = {b.x, b.y, b.z, b.w};
            #pragma unroll
            for (int r = 0; r < 4; ++r)
                #pragma unroll
                for (int c = 0; c < 4; ++c)
                    acc[r][c] += ar[r] * br[c];
        }
        __syncthreads();
    }
    float4 be = *(const float4*)&b_enc[e * D_ + n0 + tx * 4];
    #pragma unroll
    for (int r = 0; r < 4; ++r) {
        int b = b0 + ty * 4 + r;
        float4 o;
        o.x = acc[r][0] + be.x; o.y = acc[r][1] + be.y;
        o.z = acc[r][2] + be.z; o.w = acc[r][3] + be.w;
        *(float4*)&out[((size_t)e * B_ + b) * D_ + n0 + tx * 4] = o;
    }
}

__global__ __launch_bounds__(256) void dec_score(const float* __restrict__ out,
                                                 const float* __restrict__ W_dec,
                                                 const float* __restrict__ b_dec,
                                                 const float* __restrict__ x,
                                                 float* __restrict__ cbuf)
{
    __shared__ float As[16][68];
    __shared__ float Bs[16][68];
    const int btile = blockIdx.x;
    const int es    = blockIdx.y;
    const int e = es / 13;
    const int s = es % 13;
    const int b0 = btile * 64;
    const int fbase = s * SUBW_;
    const int tid = threadIdx.x;
    const int tx = tid & 15, ty = tid >> 4;
    const float* Ap = out   + (size_t)e * B_ * D_;
    const float* Wp = W_dec + (size_t)e * D_ * F_;
    const int arow = tid >> 2;
    const int ac4  = (tid & 3) * 4;
    const int bk   = tid >> 4;
    const int bn   = (tid & 15) * 4;
    float ip[4] = {}, jp[4] = {};
    for (int u = 0; u < 12; ++u) {
        const int f0 = fbase + u * 64;
        float acc[4][4] = {};
        for (int k0 = 0; k0 < D_; k0 += 16) {
            float4 av = *(const float4*)&Ap[(size_t)(b0 + arow) * D_ + k0 + ac4];
            As[ac4 + 0][arow] = av.x; As[ac4 + 1][arow] = av.y;
            As[ac4 + 2][arow] = av.z; As[ac4 + 3][arow] = av.w;
            float4 bv = *(const float4*)&Wp[(size_t)(k0 + bk) * F_ + f0 + bn];
            *(float4*)&Bs[bk][bn] = bv;
            __syncthreads();
            #pragma unroll
            for (int k = 0; k < 16; ++k) {
                float4 a = *(const float4*)&As[k][ty * 4];
                float4 b = *(const float4*)&Bs[k][tx * 4];
                float ar[4] = {a.x, a.y, a.z, a.w};
                float br[4] = {b.x, b.y, b.z, b.w};
                #pragma unroll
                for (int r = 0; r < 4; ++r)
                    #pragma unroll
                    for (int c = 0; c < 4; ++c)
                        acc[r][c] += ar[r] * br[c];
            }
            __syncthreads();
        }
        float4 bd = *(const float4*)&b_dec[(size_t)e * F_ + f0 + tx * 4];
        #pragma unroll
        for (int r = 0; r < 4; ++r) {
            int b = b0 + ty * 4 + r;
            float4 xv = *(const float4*)&x[(size_t)b * F_ + f0 + tx * 4];
            float y0 = acc[r][0] + bd.x;
            float y1 = acc[r][1] + bd.y;
            float y2 = acc[r][2] + bd.z;
            float y3 = acc[r][3] + bd.w;
            ip[r] += y0 * xv.x + y1 * xv.y + y2 * xv.z + y3 * xv.w;
            jp[r] += y0 * xv.y - y1 * xv.x + y2 * xv.w - y3 * xv.z;
        }
    }
    #pragma unroll
    for (int r = 0; r < 4; ++r) {
        float iv = ip[r], jv = jp[r];
        #pragma unroll
        for (int m = 1; m < 16; m <<= 1) {
            iv += __shfl_xor(iv, m, 64);
            jv += __shfl_xor(jv, m, 64);
        }
        if (tx == 0) {
            int b = b0 + ty * 4 + r;
            cbuf[((size_t)e * B_ + b) * NSUB_ + s] = iv * iv + jv * jv;
        }
    }
}

__global__ __launch_bounds__(256) void argmax_k(const float* __restrict__ cbuf,
                                                int* __restrict__ idx)
{
    int b = blockIdx.x * blockDim.x + threadIdx.x;
    if (b >= B_) return;
    float best = -1e30f;
    int bi = 0;
    for (int e = 0; e < E_; ++e) {
        float ssum = 0.f;
        #pragma unroll
        for (int s = 0; s < NSUB_; ++s)
            ssum += cbuf[((size_t)e * B_ + b) * NSUB_ + s];
        if (ssum > best) { best = ssum; bi = e; }
    }
    idx[b] = bi;
}

__global__ __launch_bounds__(256) void gather_k(const float* __restrict__ out,
                                                const int* __restrict__ idx,
                                                float* __restrict__ sel)
{
    int t = blockIdx.x * blockDim.x + threadIdx.x;
    int b = t >> 7;
    int c = (t & 127) * 4;
    int e = idx[b];
    *(float4*)&sel[(size_t)b * D_ + c] =
        *(const float4*)&out[((size_t)e * B_ + b) * D_ + c];
}

// ===========================================================================
extern "C" void kernel_launch(void* const* d_in, const int* in_sizes, int n_in,
                              void* d_out, int out_size, void* d_ws, size_t ws_size,
                              hipStream_t stream)
{
    const float* x     = (const float*)d_in[0];
    const float* W_enc = (const float*)d_in[1];
    const float* b_enc = (const float*)d_in[2];
    const float* W_dec = (const float*)d_in[3];
    const float* b_dec = (const float*)d_in[4];
    float* sel = (float*)d_out;

    const size_t szXplane = (size_t)B_ * F_ * sizeof(f16);        // 81,788,928
    const size_t szWplane = (size_t)E_ * F_ * D_ * sizeof(f16);   // 51,118,080
    const size_t szOplane = (size_t)E_ * B_ * D_ * sizeof(f16);   // 20,971,520
    const size_t szIJ     = (size_t)E_ * NSUB_ * 6 * 2 * B_ * sizeof(float); // 12,779,520
    const size_t need       = 2*szXplane + 2*szWplane + 2*szOplane + szIJ + (size_t)B_*4;
    const size_t needSplit2 = need + 4*szOplane;   // pH,pL x 2 partials

    if (ws_size >= need) {
        char* p = (char*)d_ws;
        f16* xhi  = (f16*)p; p += szXplane;
        f16* xlo  = (f16*)p; p += szXplane;
        f16* wthi = (f16*)p; p += szWplane;
        f16* wtlo = (f16*)p; p += szWplane;
        f16* ohi  = (f16*)p; p += szOplane;
        f16* olo  = (f16*)p; p += szOplane;
        float* ij = (float*)p; p += szIJ;
        int* idx  = (int*)p; p += (size_t)B_*4;

        split_x<<<39936, 256, 0, stream>>>(x, xhi, xlo);
        splitT_W<<<dim3(F_/64, D_/64, E_), 256, 0, stream>>>(W_enc, wthi, wtlo, F_, D_);

        if (ws_size >= needSplit2) {
            f16* pH = (f16*)p; p += 2*szOplane;
            f16* pL = (f16*)p;
            mm_enc2<<<dim3(80, 8, 2), 256, 0, stream>>>(xhi, xlo, wthi, wtlo,
                                                        nullptr, F_/2, pH, pL);
            combine_k<<<(E_*B_*D_)/(8*256), 256, 0, stream>>>(pH, pL, b_enc, 2, ohi, olo);
        } else {
            mm_enc2<<<dim3(80, 8, 1), 256, 0, stream>>>(xhi, xlo, wthi, wtlo,
                                                        b_enc, F_, ohi, olo);
        }
        splitT_W<<<dim3(D_/64, F_/64, E_), 256, 0, stream>>>(W_dec, wthi, wtlo, D_, F_);
        mm_dec2<<<dim3(32, 6, 65), 256, 0, stream>>>(wthi, wtlo, ohi, olo, b_dec, x, ij);
        argmax2<<<16, 256, 0, stream>>>(ij, idx);
        gather2<<<2048, 256, 0, stream>>>(ohi, olo, idx, sel);
    } else {
        float* out  = (float*)d_ws;
        float* cbuf = out + (size_t)E_ * B_ * D_;
        int*   idx  = (int*)(cbuf + (size_t)E_ * B_ * NSUB_);
        enc_gemm <<<dim3(64, 40), 256, 0, stream>>>(x, W_enc, b_enc, out);
        dec_score<<<dim3(64, 65), 256, 0, stream>>>(out, W_dec, b_dec, x, cbuf);
        argmax_k <<<dim3(B_ / 256), 256, 0, stream>>>(cbuf, idx);
        gather_k <<<dim3(B_ * D_ / 4 / 256), 256, 0, stream>>>(out, idx, sel);
    }
}